// Round 8
// baseline (843.691 us; speedup 1.0000x reference)
//
#include <hip/hip_runtime.h>
#include <hip/hip_fp16.h>
#include <math.h>

// HeteroGNN: 2-layer bipartite single-head GAT (users<->badges).
// R8: attack k_bucket_csr (81us x2, Occupancy 7% = 196 blocks only, WRITE
// 101MB vs 21MB ideal = scattered 4B col stores):
//   - 4x more buckets (782 blocks: ub 64 nodes/bucket, bu 256 nodes/bucket)
//   - bucket pass is now a full LDS counting sort: hist(256 bins) -> scan ->
//     rp -> scatter src into 29KB LDS buffer -> COALESCED col flush
//   - k_partition generalized to 1024 coarse bins (4 bins/thread scan,
//     10-step binary search flush)
// Gathers (lane-owned edges) and fused node kernels unchanged from R7.

#define NEG_SLOPE 0.2f
#define NS_UB 4
#define SHARD_DIV 50000
#define PART_PER 4880  // max edges per partition block (LDS sort buffer)
#define BK_CAP 7424    // max edges per bucket (LDS sort buffer, 29.7KB)

__device__ __forceinline__ float lrelu(float x) { return x > 0.f ? x : NEG_SLOPE * x; }

// ---------------- fused dense node kernel ----------------
template <int F, int C, bool RELU_IN, typename HT>
__global__ void k_nodes(const float* __restrict__ x, const float* __restrict__ Ws,
                        const float* __restrict__ a_s, const float* __restrict__ Wd_o,
                        const float* __restrict__ a_d_o, HT* __restrict__ hs,
                        float* __restrict__ alpha_s, float* __restrict__ alpha_d, int N) {
  __shared__ float sW[F * C];
  __shared__ float sa[C];
  __shared__ float sv[F];
  for (int i = threadIdx.x; i < F * C; i += blockDim.x) sW[i] = Ws[i];
  if (threadIdx.x < C) sa[threadIdx.x] = a_s[threadIdx.x];
  if (threadIdx.x < F) {
    float s = 0.f;
    for (int c = 0; c < C; ++c) s += Wd_o[threadIdx.x * C + c] * a_d_o[c];
    sv[threadIdx.x] = s;
  }
  __syncthreads();
  int n = blockIdx.x * blockDim.x + threadIdx.x;
  if (n >= N) return;
  float acc[C];
#pragma unroll
  for (int c = 0; c < C; ++c) acc[c] = 0.f;
  float ad = 0.f;
  const float* xr = x + (size_t)n * F;
#pragma unroll 4
  for (int f = 0; f < F; ++f) {
    float xv = xr[f];
    if (RELU_IN) xv = fmaxf(xv, 0.f);
#pragma unroll
    for (int c = 0; c < C; ++c) acc[c] += xv * sW[f * C + c];
    ad += xv * sv[f];
  }
  float al = 0.f;
#pragma unroll
  for (int c = 0; c < C; ++c) {
    hs[(size_t)n * C + c] = (HT)acc[c];
    al += acc[c] * sa[c];
  }
  alpha_s[n] = al;
  alpha_d[n] = ad;
}

// ---------------- CSR build ----------------

// pass 1: LDS counting sort by coarse bucket (dst>>shift, up to 1024 bins),
// coalesced u32 flush: part value = (dst_local << 18) | src.
__global__ void k_partition(const int* __restrict__ src, const int* __restrict__ dst,
                            int nE, int shift, int mask, int nbuck,
                            unsigned* __restrict__ part, int cap,
                            int* __restrict__ bcnt) {
  __shared__ unsigned s_sorted[PART_PER];
  __shared__ int h[1025];     // counts, then runstart bounds
  __shared__ int ps[256];
  __shared__ int resb[1024];  // reserved global base per bin
  __shared__ int curb[1024];
  int per = (nE + gridDim.x - 1) / gridDim.x;
  int beg = blockIdx.x * per;
  int end = min(beg + per, nE);
  int cnt = end - beg;
  int t = threadIdx.x;
  for (int i = t; i < 1024; i += 256) h[i] = 0;
  __syncthreads();
  for (int i = beg + t; i < end; i += 256) atomicAdd(&h[dst[i] >> shift], 1);
  __syncthreads();
  int vv[4], tp[4];
  int sum = 0;
#pragma unroll
  for (int k = 0; k < 4; ++k) {
    int bin = t * 4 + k;
    vv[k] = h[bin];
    tp[k] = sum;
    sum += vv[k];
  }
  ps[t] = sum;
  __syncthreads();
  for (int off = 1; off < 256; off <<= 1) {
    int u = (t >= off) ? ps[t - off] : 0;
    __syncthreads();
    ps[t] += u;
    __syncthreads();
  }
  int te = ps[t] - sum;
  int rb[4];
#pragma unroll
  for (int k = 0; k < 4; ++k) {
    int bin = t * 4 + k;
    rb[k] = (bin < nbuck && vv[k] > 0) ? atomicAdd(&bcnt[bin], vv[k]) : 0;
  }
  __syncthreads();  // all h reads done before overwrite
#pragma unroll
  for (int k = 0; k < 4; ++k) {
    int bin = t * 4 + k;
    int excl = te + tp[k];
    h[bin] = excl;
    curb[bin] = excl;
    resb[bin] = rb[k];
  }
  if (t == 255) h[1024] = ps[255];  // == cnt
  __syncthreads();
  for (int i = beg + t; i < end; i += 256) {
    int d = dst[i];
    int b = d >> shift;
    int r = atomicAdd(&curb[b], 1);
    s_sorted[r] = ((unsigned)(d & mask) << 18) | (unsigned)src[i];
  }
  __syncthreads();
  for (int i = t; i < cnt; i += 256) {
    int lo = 0, hi = 1024;  // find b: h[b] <= i < h[b+1]
    while (hi - lo > 1) {
      int mid = (lo + hi) >> 1;
      if (h[mid] <= i) lo = mid; else hi = mid;
    }
    int p = resb[lo] + (i - h[lo]);
    if (p < cap) part[(size_t)lo * cap + p] = s_sorted[i];
  }
}

__global__ void k_scanb(const int* __restrict__ bcnt, int* __restrict__ bbase, int nbuck) {
  __shared__ int lds[1024];
  int t = threadIdx.x;
  int v = (t < nbuck) ? bcnt[t] : 0;
  lds[t] = v;
  __syncthreads();
  for (int off = 1; off < 1024; off <<= 1) {
    int u = (t >= off) ? lds[t - off] : 0;
    __syncthreads();
    lds[t] += u;
    __syncthreads();
  }
  if (t < nbuck) bbase[t] = lds[t] - v;
}

// pass 2: one block per bucket (<=256 bins = npb*ns): hist -> scan -> rp ->
// LDS sort of src ids -> coalesced col flush.
__global__ void k_bucket_csr(const unsigned* __restrict__ part,
                             const int* __restrict__ bcnt, const int* __restrict__ bbase,
                             int cap, int* __restrict__ rp2, int* __restrict__ col,
                             int N, int nbuck, int npb, int ns, int sdiv) {
  __shared__ unsigned s_sorted[BK_CAP];
  __shared__ int hist[256];
  __shared__ int ps2[256];
  __shared__ int cur[256];
  int b = blockIdx.x;
  int t = threadIdx.x;
  int node0 = b * npb;
  int cnt = min(bcnt[b], cap);
  int base = bbase[b];
  const unsigned* pp = part + (size_t)b * cap;
  hist[t] = 0;
  __syncthreads();
  for (int i = t; i < cnt; i += 256) {
    unsigned e = pp[i];
    int dl = (int)(e >> 18);
    int sv = (int)(e & 0x3FFFFu);
    int bin = dl * ns + ((ns == 1) ? 0 : sv / sdiv);
    atomicAdd(&hist[bin], 1);
  }
  __syncthreads();
  int v = hist[t];
  ps2[t] = v;
  __syncthreads();
  for (int off = 1; off < 256; off <<= 1) {
    int u = (t >= off) ? ps2[t - off] : 0;
    __syncthreads();
    ps2[t] += u;
    __syncthreads();
  }
  int excl = ps2[t] - v;
  int node = node0 + t / ns;
  if (node < N) rp2[(size_t)node0 * ns + t] = base + excl;
  if (b == nbuck - 1 && t == 0) rp2[(size_t)N * ns] = base + cnt;
  cur[t] = excl;
  __syncthreads();
  for (int i = t; i < cnt; i += 256) {
    unsigned e = pp[i];
    int dl = (int)(e >> 18);
    int sv = (int)(e & 0x3FFFFu);
    int bin = dl * ns + ((ns == 1) ? 0 : sv / sdiv);
    int r = atomicAdd(&cur[bin], 1);
    s_sorted[r] = (unsigned)sv;
  }
  __syncthreads();
  for (int i = t; i < cnt; i += 256) col[base + i] = (int)s_sorted[i];
}

// ---------------- gathers: lane-owned edges, GROUP=16 ----------------

template <int C, typename HT>
__device__ __forceinline__ void load_row(const HT* __restrict__ hs, int s, float (&row)[C]) {
  if constexpr (sizeof(HT) == 2 && C == 16) {
    union { uint4 v[2]; __half h[16]; } buf;
    const uint4* hv = (const uint4*)(hs + (size_t)s * 16);
    buf.v[0] = hv[0];
    buf.v[1] = hv[1];
#pragma unroll
    for (int c = 0; c < 16; ++c) row[c] = __half2float(buf.h[c]);
  } else if constexpr (sizeof(HT) == 4 && C == 2) {
    float2 v = *(const float2*)((const float*)hs + (size_t)s * 2);
    row[0] = v.x;
    row[1] = v.y;
  } else {
#pragma unroll
    for (int c = 0; c < C; ++c) row[c] = (float)hs[(size_t)s * C + c];
  }
}

template <int C, typename HT>
__global__ void k_gather16(const int* __restrict__ rp, int rs, const int* __restrict__ col,
                           const float* __restrict__ as, const float* __restrict__ ad,
                           const HT* __restrict__ hs, const float* __restrict__ b,
                           float* __restrict__ out, int N) {
  int t = blockIdx.x * blockDim.x + threadIdx.x;
  int n = t >> 4;
  if (n >= N) return;
  int j = t & 15;
  int beg = rp[(size_t)n * rs], end = rp[(size_t)(n + 1) * rs];
  float adv = ad[n];
  float acc[C];
#pragma unroll
  for (int c = 0; c < C; ++c) acc[c] = 0.f;
  float se = 0.f;
  for (int k = beg + j; k < end; k += 16) {
    int s = col[k];
    float w = __expf(lrelu(as[s] + adv));
    se += w;
    float row[C];
    load_row<C, HT>(hs, s, row);
#pragma unroll
    for (int c = 0; c < C; ++c) acc[c] += w * row[c];
  }
#pragma unroll
  for (int m = 1; m < 16; m <<= 1) {
    se += __shfl_xor(se, m, 16);
#pragma unroll
    for (int c = 0; c < C; ++c) acc[c] += __shfl_xor(acc[c], m, 16);
  }
  if (j == 0) {
    float inv = 1.f / (se + 1e-16f);
#pragma unroll
    for (int c = 0; c < C; ++c) out[(size_t)n * C + c] = acc[c] * inv + b[c];
  }
}

template <int C>
__global__ void k_gpart16(const int* __restrict__ rp2, const int* __restrict__ col,
                          const float* __restrict__ as, const float* __restrict__ ad,
                          const __half* __restrict__ hs, float* __restrict__ acc_g,
                          float* __restrict__ se_g, int N, int s, int first) {
  int t = blockIdx.x * blockDim.x + threadIdx.x;
  int n = t >> 4;
  if (n >= N) return;
  int j = t & 15;
  int beg = rp2[(size_t)n * NS_UB + s], end = rp2[(size_t)n * NS_UB + s + 1];
  float adv = ad[n];
  float acc[C];
#pragma unroll
  for (int c = 0; c < C; ++c) acc[c] = 0.f;
  float se = 0.f;
  for (int k = beg + j; k < end; k += 16) {
    int sv = col[k];
    float w = __expf(lrelu(as[sv] + adv));
    se += w;
    float row[C];
    load_row<C, __half>(hs, sv, row);
#pragma unroll
    for (int c = 0; c < C; ++c) acc[c] += w * row[c];
  }
#pragma unroll
  for (int m = 1; m < 16; m <<= 1) {
    se += __shfl_xor(se, m, 16);
#pragma unroll
    for (int c = 0; c < C; ++c) acc[c] += __shfl_xor(acc[c], m, 16);
  }
  if (j == 0) {
    float* o = acc_g + (size_t)n * C;
    if (first) {
#pragma unroll
      for (int c = 0; c < C; ++c) o[c] = acc[c];
      se_g[n] = se;
    } else {
#pragma unroll
      for (int c = 0; c < C; ++c) o[c] += acc[c];
      se_g[n] += se;
    }
  }
}

template <int C>
__global__ void k_gfin(const float* __restrict__ acc_g, const float* __restrict__ se_g,
                       const float* __restrict__ b, float* __restrict__ out, int N) {
  int t = blockIdx.x * blockDim.x + threadIdx.x;
  if (t >= N * C) return;
  int n = t / C, c = t % C;
  out[t] = acc_g[t] / (se_g[n] + 1e-16f) + b[c];
}

extern "C" void kernel_launch(void* const* d_in, const int* in_sizes, int n_in,
                              void* d_out, int out_size, void* d_ws, size_t ws_size,
                              hipStream_t stream) {
  const int NU = 200000, NB = 50000;
  const float* x_user  = (const float*)d_in[0];
  const float* x_badge = (const float*)d_in[1];
  const int* ub_src = (const int*)d_in[2];
  const int* ub_dst = (const int*)d_in[3];
  const int* bu_src = (const int*)d_in[4];
  const int* bu_dst = (const int*)d_in[5];
  const int nE = in_sizes[2];

  const float* W1_ub_s = (const float*)d_in[8];
  const float* W1_ub_d = (const float*)d_in[9];
  const float* a1_ub_s = (const float*)d_in[10];
  const float* a1_ub_d = (const float*)d_in[11];
  const float* b1_ub   = (const float*)d_in[12];
  const float* W2_ub_s = (const float*)d_in[13];
  const float* W2_ub_d = (const float*)d_in[14];
  const float* a2_ub_s = (const float*)d_in[15];
  const float* a2_ub_d = (const float*)d_in[16];
  const float* b2_ub   = (const float*)d_in[17];
  const float* W1_bu_s = (const float*)d_in[18];
  const float* W1_bu_d = (const float*)d_in[19];
  const float* a1_bu_s = (const float*)d_in[20];
  const float* a1_bu_d = (const float*)d_in[21];
  const float* b1_bu   = (const float*)d_in[22];
  const float* W2_bu_s = (const float*)d_in[23];
  const float* W2_bu_d = (const float*)d_in[24];
  const float* a2_bu_s = (const float*)d_in[25];
  const float* a2_bu_d = (const float*)d_in[26];
  const float* b2_bu   = (const float*)d_in[27];

  // bucket geometry: ub 64 nodes/bucket (shift 6), bu 256 nodes/bucket (shift 8)
  const int nbk_ub = (NB + 63) / 64;      // 782
  const int nbk_bu = (NU + 255) / 256;    // 782
  double m_ub = (double)nE * 64.0 / NB;
  double m_bu = (double)nE * 256.0 / NU;
  int cap_ub = (int)(m_ub + 8.0 * sqrt(m_ub) + 128.0);
  int cap_bu = (int)(m_bu + 8.0 * sqrt(m_bu) + 128.0);
  if (cap_ub > BK_CAP) cap_ub = BK_CAP;
  if (cap_bu > BK_CAP) cap_bu = BK_CAP;
  const int pblocks = (nE + PART_PER - 1) / PART_PER;

  // ---- workspace carve-up ----
  char* wsb = (char*)d_ws;
  size_t off = 0;
  auto ialloc = [&](size_t n) { int* p = (int*)(wsb + off); off += n * 4; return p; };
  int* rp2_ub  = ialloc((size_t)NB * NS_UB + 1);
  int* rp_bu   = ialloc(NU + 1);
  int* col_ub  = ialloc(nE);
  int* col_bu  = ialloc(nE);
  int* bcnt_ub = ialloc(1024);
  int* bcnt_bu = ialloc(1024);
  int* bbase_ub= ialloc(1024);
  int* bbase_bu= ialloc(1024);
  off = (off + 15) & ~(size_t)15;
  // UNION: u32 part buffer (dead after each bucket pass) overlays the pool.
  char* pool = wsb + off;
  unsigned* part = (unsigned*)pool;
  size_t poff = 0;
  auto falloc = [&](size_t n) { float* p = (float*)(pool + poff); poff += n * 4; return p; };
  auto halloc = [&](size_t n) { __half* p = (__half*)(pool + poff); poff += n * 2; return p; };
  __half* hs_u1 = halloc((size_t)NU * 16);
  __half* hs_b1 = halloc((size_t)NB * 16);
  float* hu     = falloc((size_t)NU * 16);
  float* hb     = falloc((size_t)NB * 16);
  float* as_u1  = falloc(NU);
  float* ad_b1  = falloc(NB);
  float* as_b1  = falloc(NB);
  float* ad_u1  = falloc(NU);
  float* hs2_ub = falloc((size_t)NU * 2);
  float* as2_ub = falloc(NU);
  float* ad2_ub = falloc(NB);
  float* hs2_bu = falloc((size_t)NB * 2);
  float* as2_bu = falloc(NB);
  float* ad2_bu = falloc(NU);
  float* acc_ub = falloc((size_t)NB * 16);
  float* se_ub  = falloc(NB);
  (void)ws_size;

  float* ou = (float*)d_out;                   // [NU,2]
  float* ob = (float*)d_out + (size_t)NU * 2;  // [NB,2]

  dim3 blk(256);
  auto g = [](int n) { return dim3((n + 255) / 256); };

  // ===== CSR build (sequential per graph; part buffer reused) =====
  hipMemsetAsync(bcnt_ub, 0, 2048 * 4, stream);
  k_partition<<<dim3(pblocks), blk, 0, stream>>>(ub_src, ub_dst, nE, 6, 63, nbk_ub,
                                                 part, cap_ub, bcnt_ub);
  k_scanb<<<dim3(1), dim3(1024), 0, stream>>>(bcnt_ub, bbase_ub, nbk_ub);
  k_bucket_csr<<<dim3(nbk_ub), blk, 0, stream>>>(part, bcnt_ub, bbase_ub, cap_ub,
                                                 rp2_ub, col_ub, NB, nbk_ub,
                                                 64, NS_UB, SHARD_DIV);
  k_partition<<<dim3(pblocks), blk, 0, stream>>>(bu_src, bu_dst, nE, 8, 255, nbk_bu,
                                                 part, cap_bu, bcnt_bu);
  k_scanb<<<dim3(1), dim3(1024), 0, stream>>>(bcnt_bu, bbase_bu, nbk_bu);
  k_bucket_csr<<<dim3(nbk_bu), blk, 0, stream>>>(part, bcnt_bu, bbase_bu, cap_bu,
                                                 rp_bu, col_bu, NU, nbk_bu,
                                                 256, 1, 1 << 30);

  // ===== layer 1 node transforms (fused; each x read once; part now dead) =====
  k_nodes<64, 16, false, __half><<<g(NU), blk, 0, stream>>>(
      x_user, W1_ub_s, a1_ub_s, W1_bu_d, a1_bu_d, hs_u1, as_u1, ad_u1, NU);
  k_nodes<64, 16, false, __half><<<g(NB), blk, 0, stream>>>(
      x_badge, W1_bu_s, a1_bu_s, W1_ub_d, a1_ub_d, hs_b1, as_b1, ad_b1, NB);

  // ===== layer 1 gathers =====
  for (int s = 0; s < NS_UB; ++s)
    k_gpart16<16><<<g(NB * 16), blk, 0, stream>>>(rp2_ub, col_ub, as_u1, ad_b1, hs_u1,
                                                  acc_ub, se_ub, NB, s, s == 0 ? 1 : 0);
  k_gfin<16><<<g(NB * 16), blk, 0, stream>>>(acc_ub, se_ub, b1_ub, hb, NB);
  k_gather16<16, __half><<<g(NU * 16), blk, 0, stream>>>(rp_bu, 1, col_bu, as_b1, ad_u1,
                                                         hs_b1, b1_bu, hu, NU);

  // ===== layer 2 node transforms (fused, relu folded) =====
  k_nodes<16, 2, true, float><<<g(NU), blk, 0, stream>>>(
      hu, W2_ub_s, a2_ub_s, W2_bu_d, a2_bu_d, hs2_ub, as2_ub, ad2_bu, NU);
  k_nodes<16, 2, true, float><<<g(NB), blk, 0, stream>>>(
      hb, W2_bu_s, a2_bu_s, W2_ub_d, a2_ub_d, hs2_bu, as2_bu, ad2_ub, NB);

  // ===== layer 2 gathers =====
  k_gather16<2, float><<<g(NB * 16), blk, 0, stream>>>(rp2_ub, NS_UB, col_ub, as2_ub,
                                                       ad2_ub, hs2_ub, b2_ub, ob, NB);
  k_gather16<2, float><<<g(NU * 16), blk, 0, stream>>>(rp_bu, 1, col_bu, as2_bu,
                                                       ad2_bu, hs2_bu, b2_bu, ou, NU);
}

// Round 9
// 667.541 us; speedup vs baseline: 1.2639x; 1.2639x over previous
//
#include <hip/hip_runtime.h>
#include <hip/hip_fp16.h>
#include <math.h>

// HeteroGNN: 2-layer bipartite single-head GAT (users<->badges).
// R9: three-stage CSR build, every stage coalesced (R8 post-mortem: flush
// run length = PART_PER/nbins; 1024 bins -> 19B runs -> 169us partition):
//   1) k_partition: R7's proven 256-coarse-bin LDS counting sort (76B runs)
//   2) k_refine: block per coarse bucket, 4-way split via wave-ballot
//      aggregated cursors (64B runs) into PADDED per-fine-bucket slots
//   3) k_bucket_fine: R8's LDS-staged sort, IN PLACE in the slot; the slot
//      is the col array; rp2 is slot-relative [784][257]. No scanb, no col.
// Plus: hu/hb fp16 (layer-2 reads halve), gfin folded into last gpart shard.

#define NEG_SLOPE 0.2f
#define PART_PER 4880   // edges per partition block (LDS sort buffer)
#define NBC 196         // coarse buckets per graph
#define NBF 784         // fine buckets = NBC*4
#define CAPF 7424       // padded fine-bucket capacity (29.7KB LDS stage)
#define SHARD_DIV 50000

__device__ __forceinline__ float lrelu(float x) { return x > 0.f ? x : NEG_SLOPE * x; }
__device__ __forceinline__ float cvt(float v) { return v; }
__device__ __forceinline__ float cvt(__half v) { return __half2float(v); }

// ---------------- fused dense node kernel ----------------
// hs[n,:] = (relu?)x[n,:] @ Ws ; alpha_s[n] = hs[n,:] @ a_s ;
// alpha_d[n] = (relu?)x[n,:] @ (Wd_o @ a_d_o)
template <int F, int C, bool RELU_IN, typename XT, typename HT>
__global__ void k_nodes(const XT* __restrict__ x, const float* __restrict__ Ws,
                        const float* __restrict__ a_s, const float* __restrict__ Wd_o,
                        const float* __restrict__ a_d_o, HT* __restrict__ hs,
                        float* __restrict__ alpha_s, float* __restrict__ alpha_d, int N) {
  __shared__ float sW[F * C];
  __shared__ float sa[C];
  __shared__ float sv[F];
  for (int i = threadIdx.x; i < F * C; i += blockDim.x) sW[i] = Ws[i];
  if (threadIdx.x < C) sa[threadIdx.x] = a_s[threadIdx.x];
  if (threadIdx.x < F) {
    float s = 0.f;
    for (int c = 0; c < C; ++c) s += Wd_o[threadIdx.x * C + c] * a_d_o[c];
    sv[threadIdx.x] = s;
  }
  __syncthreads();
  int n = blockIdx.x * blockDim.x + threadIdx.x;
  if (n >= N) return;
  float acc[C];
#pragma unroll
  for (int c = 0; c < C; ++c) acc[c] = 0.f;
  float ad = 0.f;
  const XT* xr = x + (size_t)n * F;
#pragma unroll 4
  for (int f = 0; f < F; ++f) {
    float xv = cvt(xr[f]);
    if (RELU_IN) xv = fmaxf(xv, 0.f);
#pragma unroll
    for (int c = 0; c < C; ++c) acc[c] += xv * sW[f * C + c];
    ad += xv * sv[f];
  }
  float al = 0.f;
#pragma unroll
  for (int c = 0; c < C; ++c) {
    if constexpr (sizeof(HT) == 2)
      hs[(size_t)n * C + c] = __float2half(acc[c]);
    else
      hs[(size_t)n * C + c] = acc[c];
    al += acc[c] * sa[c];
  }
  alpha_s[n] = al;
  alpha_d[n] = ad;
}

// ---------------- CSR stage 1: coarse partition (256 bins, R7) ----------------
__global__ void k_partition(const int* __restrict__ src, const int* __restrict__ dst,
                            int nE, int shift, int mask, int nbuck,
                            unsigned* __restrict__ part, int cap,
                            int* __restrict__ bcnt) {
  __shared__ unsigned s_sorted[PART_PER];
  __shared__ int h[257];
  __shared__ int ps[256];
  __shared__ int resb[256];
  __shared__ int cur[256];
  int per = (nE + gridDim.x - 1) / gridDim.x;
  int beg = blockIdx.x * per;
  int end = min(beg + per, nE);
  int cnt = end - beg;
  int t = threadIdx.x;
  h[t] = 0;
  __syncthreads();
  for (int i = beg + t; i < end; i += 256) atomicAdd(&h[dst[i] >> shift], 1);
  __syncthreads();
  int v = h[t];
  ps[t] = v;
  __syncthreads();
  for (int off = 1; off < 256; off <<= 1) {
    int u = (t >= off) ? ps[t - off] : 0;
    __syncthreads();
    ps[t] += u;
    __syncthreads();
  }
  int excl = ps[t] - v;
  resb[t] = (t < nbuck && v > 0) ? atomicAdd(&bcnt[t], v) : 0;
  __syncthreads();
  h[t] = excl;
  cur[t] = excl;
  if (t == 255) h[256] = excl + v;
  __syncthreads();
  for (int i = beg + t; i < end; i += 256) {
    int d = dst[i];
    int b = d >> shift;
    int r = atomicAdd(&cur[b], 1);
    s_sorted[r] = ((unsigned)(d & mask) << 18) | (unsigned)src[i];
  }
  __syncthreads();
  for (int i = t; i < cnt; i += 256) {
    int lo = 0, hi = 256;
    while (hi - lo > 1) {
      int mid = (lo + hi) >> 1;
      if (h[mid] <= i) lo = mid; else hi = mid;
    }
    int p = resb[lo] + (i - h[lo]);
    if (p < cap) part[(size_t)lo * cap + p] = s_sorted[i];
  }
}

// ---------------- CSR stage 2: refine coarse->4 fine buckets ----------------
// Wave-ballot aggregated cursors: each wave's stores per sub-bucket form a
// ~16-edge (64B) contiguous run. Output into padded slot fidx*CAPF.
__global__ void k_refine(const unsigned* __restrict__ part_c,
                         const int* __restrict__ bcnt_c, int cap_c,
                         unsigned* __restrict__ part_f, int* __restrict__ bcnt_f,
                         int subshift, unsigned fmask) {
  __shared__ int gcur[4];
  int b = blockIdx.x, t = threadIdx.x, lane = t & 63;
  int cnt = min(bcnt_c[b], cap_c);
  const unsigned* pp = part_c + (size_t)b * cap_c;
  if (t < 4) gcur[t] = 0;
  __syncthreads();
  int iters = (cnt + blockDim.x - 1) / blockDim.x;
  for (int it = 0; it < iters; ++it) {
    int i = it * blockDim.x + t;
    bool valid = i < cnt;
    unsigned e = valid ? pp[i] : 0u;
    int sb = (int)(e >> 18) >> subshift;  // 0..3
    unsigned long long m0 = __ballot(valid && sb == 0);
    unsigned long long m1 = __ballot(valid && sb == 1);
    unsigned long long m2 = __ballot(valid && sb == 2);
    unsigned long long m3 = __ballot(valid && sb == 3);
    int r0 = 0, r1 = 0, r2 = 0, r3 = 0;
    if (lane == 0) {
      r0 = atomicAdd(&gcur[0], (int)__popcll(m0));
      r1 = atomicAdd(&gcur[1], (int)__popcll(m1));
      r2 = atomicAdd(&gcur[2], (int)__popcll(m2));
      r3 = atomicAdd(&gcur[3], (int)__popcll(m3));
    }
    r0 = __shfl(r0, 0); r1 = __shfl(r1, 0); r2 = __shfl(r2, 0); r3 = __shfl(r3, 0);
    if (valid) {
      unsigned long long mm = sb == 0 ? m0 : (sb == 1 ? m1 : (sb == 2 ? m2 : m3));
      int rb = sb == 0 ? r0 : (sb == 1 ? r1 : (sb == 2 ? r2 : r3));
      int pos = rb + (int)__popcll(mm & ((1ull << lane) - 1ull));
      if (pos < CAPF) {
        unsigned fdl = (e >> 18) & fmask;
        part_f[(size_t)(b * 4 + sb) * CAPF + pos] = (fdl << 18) | (e & 0x3FFFFu);
      }
    }
  }
  __syncthreads();
  if (t < 4) bcnt_f[b * 4 + t] = min(gcur[t], CAPF);
}

// ---------------- CSR stage 3: per-fine-bucket sort, IN PLACE ----------------
// rp2 layout: [NBF][257] slot-relative absolute offsets (f*CAPF + excl).
__global__ void k_bucket_fine(unsigned* __restrict__ part_f,
                              const int* __restrict__ bcnt_f, int* __restrict__ rp2,
                              int ns, int sdiv) {
  __shared__ unsigned s_sorted[CAPF];
  __shared__ int hist[256];
  __shared__ int ps2[256];
  __shared__ int cur[256];
  int f = blockIdx.x;
  int t = threadIdx.x;
  int cnt = bcnt_f[f];
  int slot = f * CAPF;
  unsigned* pp = part_f + (size_t)slot;
  hist[t] = 0;
  __syncthreads();
  for (int i = t; i < cnt; i += 256) {
    unsigned e = pp[i];
    int fdl = (int)(e >> 18);
    int sv = (int)(e & 0x3FFFFu);
    int bin = (ns == 4) ? fdl * 4 + sv / sdiv : fdl;
    atomicAdd(&hist[bin], 1);
  }
  __syncthreads();
  int v = hist[t];
  ps2[t] = v;
  __syncthreads();
  for (int off = 1; off < 256; off <<= 1) {
    int u = (t >= off) ? ps2[t - off] : 0;
    __syncthreads();
    ps2[t] += u;
    __syncthreads();
  }
  int excl = ps2[t] - v;
  rp2[f * 257 + t] = slot + excl;
  if (t == 0) rp2[f * 257 + 256] = slot + cnt;
  cur[t] = excl;
  __syncthreads();
  for (int i = t; i < cnt; i += 256) {
    unsigned e = pp[i];
    int fdl = (int)(e >> 18);
    int sv = (int)(e & 0x3FFFFu);
    int bin = (ns == 4) ? fdl * 4 + sv / sdiv : fdl;
    int r = atomicAdd(&cur[bin], 1);
    s_sorted[r] = (unsigned)sv;
  }
  __syncthreads();
  for (int i = t; i < cnt; i += 256) pp[i] = s_sorted[i];  // in-place: slot IS col
}

// ---------------- gathers: lane-owned edges, GROUP=16 ----------------

template <int C, typename HT>
__device__ __forceinline__ void load_row(const HT* __restrict__ hs, int s, float (&row)[C]) {
  if constexpr (sizeof(HT) == 2 && C == 16) {
    union { uint4 v[2]; __half h[16]; } buf;
    const uint4* hv = (const uint4*)(hs + (size_t)s * 16);
    buf.v[0] = hv[0];
    buf.v[1] = hv[1];
#pragma unroll
    for (int c = 0; c < 16; ++c) row[c] = __half2float(buf.h[c]);
  } else if constexpr (sizeof(HT) == 4 && C == 2) {
    float2 v = *(const float2*)((const float*)hs + (size_t)s * 2);
    row[0] = v.x;
    row[1] = v.y;
  } else {
#pragma unroll
    for (int c = 0; c < C; ++c) row[c] = cvt(hs[(size_t)s * C + c]);
  }
}

// full fused gather; node n -> fine bucket f = n>>LSH, local = n & ((1<<LSH)-1)
template <int C, int LSH, int NSG, typename HT, typename OT>
__global__ void k_gather16(const int* __restrict__ rp, const int* __restrict__ col,
                           const float* __restrict__ as, const float* __restrict__ ad,
                           const HT* __restrict__ hs, const float* __restrict__ b,
                           OT* __restrict__ out, int N) {
  int t = blockIdx.x * blockDim.x + threadIdx.x;
  int n = t >> 4;
  if (n >= N) return;
  int j = t & 15;
  int f = n >> LSH;
  int local = n & ((1 << LSH) - 1);
  int beg = rp[f * 257 + local * NSG];
  int end = rp[f * 257 + local * NSG + NSG];
  float adv = ad[n];
  float acc[C];
#pragma unroll
  for (int c = 0; c < C; ++c) acc[c] = 0.f;
  float se = 0.f;
  for (int k = beg + j; k < end; k += 16) {
    int s = col[k];
    float w = __expf(lrelu(as[s] + adv));
    se += w;
    float row[C];
    load_row<C, HT>(hs, s, row);
#pragma unroll
    for (int c = 0; c < C; ++c) acc[c] += w * row[c];
  }
#pragma unroll
  for (int m = 1; m < 16; m <<= 1) {
    se += __shfl_xor(se, m, 16);
#pragma unroll
    for (int c = 0; c < C; ++c) acc[c] += __shfl_xor(acc[c], m, 16);
  }
  if (j == 0) {
    float inv = 1.f / (se + 1e-16f);
#pragma unroll
    for (int c = 0; c < C; ++c) {
      float o = acc[c] * inv + b[c];
      if constexpr (sizeof(OT) == 2)
        out[(size_t)n * C + c] = __float2half(o);
      else
        out[(size_t)n * C + c] = o;
    }
  }
}

// sharded partial gather (ub layer 1). mode: 0=first(write), 1=accum,
// 2=last(accum + finalize: divide, +bias, write fp16 out).
template <int C>
__global__ void k_gpart16(const int* __restrict__ rp2, const int* __restrict__ col,
                          const float* __restrict__ as, const float* __restrict__ ad,
                          const __half* __restrict__ hs, float* __restrict__ acc_g,
                          float* __restrict__ se_g, const float* __restrict__ bias,
                          __half* __restrict__ out, int N, int s, int mode) {
  int t = blockIdx.x * blockDim.x + threadIdx.x;
  int n = t >> 4;
  if (n >= N) return;
  int j = t & 15;
  int f = n >> 6;
  int local = n & 63;
  int beg = rp2[f * 257 + local * 4 + s];
  int end = rp2[f * 257 + local * 4 + s + 1];
  float adv = ad[n];
  float acc[C];
#pragma unroll
  for (int c = 0; c < C; ++c) acc[c] = 0.f;
  float se = 0.f;
  for (int k = beg + j; k < end; k += 16) {
    int sv = col[k];
    float w = __expf(lrelu(as[sv] + adv));
    se += w;
    float row[C];
    load_row<C, __half>(hs, sv, row);
#pragma unroll
    for (int c = 0; c < C; ++c) acc[c] += w * row[c];
  }
#pragma unroll
  for (int m = 1; m < 16; m <<= 1) {
    se += __shfl_xor(se, m, 16);
#pragma unroll
    for (int c = 0; c < C; ++c) acc[c] += __shfl_xor(acc[c], m, 16);
  }
  if (j == 0) {
    float* o = acc_g + (size_t)n * C;
    if (mode == 0) {
#pragma unroll
      for (int c = 0; c < C; ++c) o[c] = acc[c];
      se_g[n] = se;
    } else if (mode == 1) {
#pragma unroll
      for (int c = 0; c < C; ++c) o[c] += acc[c];
      se_g[n] += se;
    } else {
      float st = se_g[n] + se;
      float inv = 1.f / (st + 1e-16f);
#pragma unroll
      for (int c = 0; c < C; ++c)
        out[(size_t)n * C + c] = __float2half((o[c] + acc[c]) * inv + bias[c]);
    }
  }
}

extern "C" void kernel_launch(void* const* d_in, const int* in_sizes, int n_in,
                              void* d_out, int out_size, void* d_ws, size_t ws_size,
                              hipStream_t stream) {
  const int NU = 200000, NB = 50000;
  const float* x_user  = (const float*)d_in[0];
  const float* x_badge = (const float*)d_in[1];
  const int* ub_src = (const int*)d_in[2];
  const int* ub_dst = (const int*)d_in[3];
  const int* bu_src = (const int*)d_in[4];
  const int* bu_dst = (const int*)d_in[5];
  const int nE = in_sizes[2];

  const float* W1_ub_s = (const float*)d_in[8];
  const float* W1_ub_d = (const float*)d_in[9];
  const float* a1_ub_s = (const float*)d_in[10];
  const float* a1_ub_d = (const float*)d_in[11];
  const float* b1_ub   = (const float*)d_in[12];
  const float* W2_ub_s = (const float*)d_in[13];
  const float* W2_ub_d = (const float*)d_in[14];
  const float* a2_ub_s = (const float*)d_in[15];
  const float* a2_ub_d = (const float*)d_in[16];
  const float* b2_ub   = (const float*)d_in[17];
  const float* W1_bu_s = (const float*)d_in[18];
  const float* W1_bu_d = (const float*)d_in[19];
  const float* a1_bu_s = (const float*)d_in[20];
  const float* a1_bu_d = (const float*)d_in[21];
  const float* b1_bu   = (const float*)d_in[22];
  const float* W2_bu_s = (const float*)d_in[23];
  const float* W2_bu_d = (const float*)d_in[24];
  const float* a2_bu_s = (const float*)d_in[25];
  const float* a2_bu_d = (const float*)d_in[26];
  const float* b2_bu   = (const float*)d_in[27];

  // coarse: ub 256 nodes/bucket (shift 8), bu 1024 nodes/bucket (shift 10)
  double m_c = (double)nE / NBC;
  int cap_c = (int)(m_c + 8.0 * sqrt(m_c) + 256.0);
  const int pblocks = (nE + PART_PER - 1) / PART_PER;

  // ---- workspace carve-up ----
  char* wsb = (char*)d_ws;
  size_t off = 0;
  auto ialloc = [&](size_t n) { int* p = (int*)(wsb + off); off += n * 4; return p; };
  int* rp2_ub   = ialloc((size_t)NBF * 257);
  int* rp2_bu   = ialloc((size_t)NBF * 257);
  int* bcnt_c   = ialloc(512);          // [0:256) ub, [256:512) bu; one memset
  int* bcnt_f_ub= ialloc(NBF);
  int* bcnt_f_bu= ialloc(NBF);
  off = (off + 15) & ~(size_t)15;
  unsigned* part_f_ub = (unsigned*)(wsb + off); off += (size_t)NBF * CAPF * 4;
  unsigned* part_f_bu = (unsigned*)(wsb + off); off += (size_t)NBF * CAPF * 4;
  off = (off + 15) & ~(size_t)15;
  // UNION region: part_c (dead after refine of graph 2) overlaid by node pool
  char* pool = wsb + off;
  unsigned* part_c = (unsigned*)pool;
  size_t poff = 0;
  auto falloc = [&](size_t n) { float* p = (float*)(pool + poff); poff += n * 4; return p; };
  auto halloc = [&](size_t n) { __half* p = (__half*)(pool + poff); poff += n * 2; return p; };
  __half* hs_u1 = halloc((size_t)NU * 16);
  __half* hs_b1 = halloc((size_t)NB * 16);
  __half* hu    = halloc((size_t)NU * 16);
  __half* hb    = halloc((size_t)NB * 16);
  float* as_u1  = falloc(NU);
  float* ad_b1  = falloc(NB);
  float* as_b1  = falloc(NB);
  float* ad_u1  = falloc(NU);
  float* hs2_ub = falloc((size_t)NU * 2);
  float* as2_ub = falloc(NU);
  float* ad2_ub = falloc(NB);
  float* hs2_bu = falloc((size_t)NB * 2);
  float* as2_bu = falloc(NB);
  float* ad2_bu = falloc(NU);
  float* acc_ub = falloc((size_t)NB * 16);
  float* se_ub  = falloc(NB);
  (void)ws_size;

  float* ou = (float*)d_out;                   // [NU,2]
  float* ob = (float*)d_out + (size_t)NU * 2;  // [NB,2]
  const int* col_ub = (const int*)part_f_ub;   // after in-place sort
  const int* col_bu = (const int*)part_f_bu;

  dim3 blk(256);
  auto g = [](int n) { return dim3((n + 255) / 256); };

  // ===== CSR build: partition -> refine -> bucket sort (per graph) =====
  hipMemsetAsync(bcnt_c, 0, 512 * 4, stream);
  k_partition<<<dim3(pblocks), blk, 0, stream>>>(ub_src, ub_dst, nE, 8, 255, NBC,
                                                 part_c, cap_c, bcnt_c);
  k_refine<<<dim3(NBC), dim3(1024), 0, stream>>>(part_c, bcnt_c, cap_c,
                                                 part_f_ub, bcnt_f_ub, 6, 63u);
  k_bucket_fine<<<dim3(NBF), blk, 0, stream>>>(part_f_ub, bcnt_f_ub, rp2_ub,
                                               4, SHARD_DIV);
  k_partition<<<dim3(pblocks), blk, 0, stream>>>(bu_src, bu_dst, nE, 10, 1023, NBC,
                                                 part_c, cap_c, bcnt_c + 256);
  k_refine<<<dim3(NBC), dim3(1024), 0, stream>>>(part_c, bcnt_c + 256, cap_c,
                                                 part_f_bu, bcnt_f_bu, 8, 255u);
  k_bucket_fine<<<dim3(NBF), blk, 0, stream>>>(part_f_bu, bcnt_f_bu, rp2_bu,
                                               1, 1 << 30);

  // ===== layer 1 node transforms (part_c now dead; pool writes begin) =====
  k_nodes<64, 16, false, float, __half><<<g(NU), blk, 0, stream>>>(
      x_user, W1_ub_s, a1_ub_s, W1_bu_d, a1_bu_d, hs_u1, as_u1, ad_u1, NU);
  k_nodes<64, 16, false, float, __half><<<g(NB), blk, 0, stream>>>(
      x_badge, W1_bu_s, a1_bu_s, W1_ub_d, a1_ub_d, hs_b1, as_b1, ad_b1, NB);

  // ===== layer 1 gathers =====
  // ub (dst=badge): 4 src-shards (1.6MB fp16 hs slice each, L2-resident);
  // last shard finalizes (divide + bias -> hb fp16).
  for (int s = 0; s < 4; ++s)
    k_gpart16<16><<<g(NB * 16), blk, 0, stream>>>(rp2_ub, col_ub, as_u1, ad_b1, hs_u1,
                                                  acc_ub, se_ub, b1_ub, hb, NB, s,
                                                  s == 0 ? 0 : (s == 3 ? 2 : 1));
  // bu (dst=user): 1.6MB fp16 table, single pass -> hu fp16
  k_gather16<16, 8, 1, __half, __half><<<g(NU * 16), blk, 0, stream>>>(
      rp2_bu, col_bu, as_b1, ad_u1, hs_b1, b1_bu, hu, NU);

  // ===== layer 2 node transforms (fp16 in, relu folded) =====
  k_nodes<16, 2, true, __half, float><<<g(NU), blk, 0, stream>>>(
      hu, W2_ub_s, a2_ub_s, W2_bu_d, a2_bu_d, hs2_ub, as2_ub, ad2_bu, NU);
  k_nodes<16, 2, true, __half, float><<<g(NB), blk, 0, stream>>>(
      hb, W2_bu_s, a2_bu_s, W2_ub_d, a2_ub_d, hs2_bu, as2_bu, ad2_ub, NB);

  // ===== layer 2 gathers (fp32 out) =====
  k_gather16<2, 6, 4, float, float><<<g(NB * 16), blk, 0, stream>>>(
      rp2_ub, col_ub, as2_ub, ad2_ub, hs2_ub, b2_ub, ob, NB);
  k_gather16<2, 8, 1, float, float><<<g(NU * 16), blk, 0, stream>>>(
      rp2_bu, col_bu, as2_bu, ad2_bu, hs2_bu, b2_bu, ou, NU);
}